// Round 1
// baseline (28.076 us; speedup 1.0000x reference)
//
#include <hip/hip_runtime.h>

#define YDIM 30
#define HWSZ 65536          // 256*256
#define NBLK 2048
#define NTHR 256
// total pixels = 8 * 65536 = 524288 = NBLK*NTHR

__global__ __launch_bounds__(NTHR) void drl_main(const float* __restrict__ out,
                                                 float* __restrict__ partial) {
    const int tid = blockIdx.x * NTHR + threadIdx.x;   // pixel index 0..524287
    const int b  = tid >> 16;                          // batch
    const int hw = tid & (HWSZ - 1);

    const float* p0 = out + ((size_t)(b * 2) * YDIM) * HWSZ + hw;  // out[b][0][y][hw]
    const float* p1 = p0 + (size_t)YDIM * HWSZ;                     // out[b][1][y][hw]

    // load out0 column into registers (all indices compile-time after unroll)
    float c0[YDIM];
#pragma unroll
    for (int y = 0; y < YDIM; ++y) c0[y] = p0[(size_t)y * HWSZ];

    // argmin of diff: diff[0] = -7, diff[1]=0, diff[29]=0, diff[y]=c0[y]-c0[y-1]
    // best starts at -7 (index 0); zeros at y=1,29 can never beat it (strict <).
    float best = -7.0f;
    int d = 0;
#pragma unroll
    for (int y = 2; y < YDIM - 1; ++y) {
        float df = c0[y] - c0[y - 1];
        if (df < best) { best = df; d = y; }
    }
    const float fd = (float)d;

    // segment sums (masked, fully unrolled, predicated)
    float sy_b = 0.f, sy_a = 0.f;
#pragma unroll
    for (int y = 0; y < YDIM; ++y) {
        if (y < d) sy_b += c0[y];
        else       sy_a += c0[y];
    }
    const float nb = fd;
    const float na = (float)YDIM - fd;
    const float nsb = fmaxf(nb, 1.f);
    const float nsa = fmaxf(na, 1.f);
    const float mean_x_b = (fd * (fd - 1.f) * 0.5f) / nsb;   // sum t, t<d  = d(d-1)/2
    const float mean_y_b = sy_b / nsb;
    const float mean_x_a = (na * (na - 1.f) * 0.5f) / nsa;   // sum (t-d), t>=d = na(na-1)/2
    const float mean_y_a = sy_a / nsa;

    float cov_b = 0.f, cov_a = 0.f;
#pragma unroll
    for (int y = 0; y < YDIM; ++y) {
        if (y < d) cov_b += ((float)y - mean_x_b) * (c0[y] - mean_y_b);
        else       cov_a += (((float)y - fd) - mean_x_a) * (c0[y] - mean_y_a);
    }
    const float var_b = nb * (nb * nb - 1.f) * (1.f / 12.f);
    const float var_a = na * (na * na - 1.f) * (1.f / 12.f);
    const float slope_b = (var_b > 0.f) ? cov_b / fmaxf(var_b, 1.f) : 0.f;
    const float slope_a = (var_a > 0.f) ? cov_a / fmaxf(var_a, 1.f) : 0.f;
    const float itc_b = fminf(fmaxf(mean_y_b - slope_b * mean_x_b, 0.f), 100.f);
    const float itc_a = fminf(fmaxf(mean_y_a - slope_a * mean_x_a, 0.f), 100.f);
    const float sc_b = fminf(fmaxf(slope_b, 0.f), 2.f);
    const float sc_a = fminf(fmaxf(slope_a, 0.f), 2.f);

    // loss accumulation vs out1 (streamed loads, unrolled)
    float acc = 0.f;
#pragma unroll
    for (int y = 0; y < YDIM; ++y) {
        float fit = (y < d) ? (sc_b * (float)y + itc_b)
                            : (sc_a * ((float)y - fd) + itc_a);
        float e = fit - p1[(size_t)y * HWSZ];
        acc += e * e;
    }

    // wave reduce (64 lanes)
#pragma unroll
    for (int off = 32; off > 0; off >>= 1) acc += __shfl_down(acc, off, 64);

    __shared__ float wsum[NTHR / 64];
    const int lane = threadIdx.x & 63;
    const int wid  = threadIdx.x >> 6;
    if (lane == 0) wsum[wid] = acc;
    __syncthreads();
    if (threadIdx.x == 0) {
        partial[blockIdx.x] = wsum[0] + wsum[1] + wsum[2] + wsum[3];
    }
}

__global__ __launch_bounds__(NTHR) void drl_reduce(const float* __restrict__ partial,
                                                   float* __restrict__ outp) {
    double s = 0.0;
    for (int i = threadIdx.x; i < NBLK; i += NTHR) s += (double)partial[i];
    __shared__ double sm[NTHR];
    sm[threadIdx.x] = s;
    __syncthreads();
    for (int st = NTHR / 2; st > 0; st >>= 1) {
        if (threadIdx.x < st) sm[threadIdx.x] += sm[threadIdx.x + st];
        __syncthreads();
    }
    if (threadIdx.x == 0) {
        const double N = (double)(8 * YDIM) * (double)HWSZ;  // 15728640
        outp[0] = (float)(sm[0] / N);
    }
}

extern "C" void kernel_launch(void* const* d_in, const int* in_sizes, int n_in,
                              void* d_out, int out_size, void* d_ws, size_t ws_size,
                              hipStream_t stream) {
    const float* out_t = (const float*)d_in[0];   // (8,2,30,256,256) f32
    // d_in[1] = target: unused by the reference loss
    float* partial = (float*)d_ws;                // 2048 floats
    float* loss    = (float*)d_out;               // scalar f32

    drl_main<<<NBLK, NTHR, 0, stream>>>(out_t, partial);
    drl_reduce<<<1, NTHR, 0, stream>>>(partial, loss);
}